// Round 1
// 538.708 us; speedup vs baseline: 1.0036x; 1.0036x over previous
//
#include <hip/hip_runtime.h>

// BoneLengthLoss: masked MSE over 32 bone lengths, B=524288, 37 kpts, fp32.
// ~485 MB input stream -> HBM floor ~77-91us.
//
// R1-R4 history: staging schemes all landed 200-250us because every variant
// drained vmcnt(0) at __syncthreads before compute -> convoy: memory idle
// during compute/issue windows, ~40% HBM duty cycle.
// R5 (this): software-pipeline with counted vmcnt + raw s_barrier (T3/T4
// 2-phase template). pred-buf / ref-buf alternate as load-dest vs
// compute-src, so loads for the NEXT phase are always in flight:
//   issue ref(t) -> vmcnt(7)  [pred(t)+mask(t) done] -> bar -> lens
//   -> lgkm(0)+bar -> issue pred(t+G)+mask(t+G) -> vmcnt(10) [ref(t) done]
//   -> bar -> acc -> lgkm(0)+bar
// Per-wave load counts are exact constants (7 pose / 3 mask), so the counted
// waits are sound. LDS 61.6KB -> 2 blocks/CU; ~60KB/CU always outstanding,
// far above the ~9KB Little's-law need -> memory never idles.

#define NKPT   37
#define ROWF   111             // floats per pose row
#define TROWS  64              // rows per tile (= lane)
#define TF4    1776            // float4 per tile per array (64*111/4)
#define WF4    444             // float4 per wave slice (6*64 + 60)
#define TMB    2368            // mask bytes per tile
#define TMW    592             // mask words per tile
#define WMW    148             // mask words per wave (2*64 + 20)
#define BLOCK  256
#define WPB    4
#define GRID   512             // 2 blocks/CU * 256 CU, 8192/512 = 16 tiles exact

constexpr int J1[32] = {1,1,1,2,3,11,11,12,13,14,15,16,12,18,20,13,19,21,16,16,24,25,24,27,29,25,28,30,17,33,34,35};
constexpr int J2[32] = {2,3,4,5,6,12,13,14,14,15,16,17,18,20,22,19,21,23,24,25,26,26,27,29,31,28,30,32,33,34,35,36};

#define WAITVM(N)  asm volatile("s_waitcnt vmcnt(" #N ")" ::: "memory")
#define WAITLGKM() asm volatile("s_waitcnt lgkmcnt(0)" ::: "memory")
#define BAR()      __builtin_amdgcn_s_barrier()

__device__ __forceinline__ void glds16(const void* g, void* l) {
    __builtin_amdgcn_global_load_lds(
        (const __attribute__((address_space(1))) void*)g,
        (__attribute__((address_space(3))) void*)l, 16, 0, 0);
}
__device__ __forceinline__ void glds4(const void* g, void* l) {
    __builtin_amdgcn_global_load_lds(
        (const __attribute__((address_space(1))) void*)g,
        (__attribute__((address_space(3))) void*)l, 4, 0, 0);
}

// ws[0]=num(f32) ws[1]=den(u32) ws[2]=mask-layout flag ws[3]=done counter
__global__ void init_detect(const unsigned int* __restrict__ mw,
                            unsigned int* __restrict__ ws) {
    const int tid = threadIdx.x;
    if (tid < 4) ws[tid] = 0u;
    __syncthreads();
    unsigned int local = 0;
    for (int i = tid; i < 1024; i += BLOCK) local |= mw[i] & 0xFFFFFF00u;
    if (__any(local != 0) && (tid & 63) == 0) atomicOr(&ws[2], 1u);
}

// 7 glds16 per wave, exec-masked tail still issues exactly once per wave.
__device__ __forceinline__ void stage_pose(const float4* __restrict__ g,
                                           float4* l, int lane) {
#pragma unroll
    for (int k = 0; k < 6; ++k) glds16(g + k * 64 + lane, l + k * 64);
    if (lane < WF4 - 384) glds16(g + 384 + lane, l + 384);
}

// 3 glds4 per wave (byte-layout mask).
__device__ __forceinline__ void stage_mask(const unsigned int* __restrict__ mb,
                                           unsigned int* md, int lane) {
    glds4(mb + lane, md);
    glds4(mb + 64 + lane, md + 64);
    if (lane < WMW - 128) glds4(mb + 128 + lane, md + 128);
}

template <int G>
__device__ __forceinline__ void do_lens(const float* __restrict__ sp,
                                        float* __restrict__ len) {
#pragma unroll
    for (int k = 0; k < 8; ++k) {
        const int a = J1[G * 8 + k] * 3, b = J2[G * 8 + k] * 3;
        float dx = sp[b] - sp[a];
        float dy = sp[b + 1] - sp[a + 1];
        float dz = sp[b + 2] - sp[a + 2];
        len[k] = __builtin_amdgcn_sqrtf(dx * dx + dy * dy + dz * dz);
    }
}

template <int G>
__device__ __forceinline__ void do_acc(const float* __restrict__ sr,
                                       const unsigned char* __restrict__ sm,
                                       const float* __restrict__ plen,
                                       float& num, unsigned int& den) {
#pragma unroll
    for (int k = 0; k < 8; ++k) {
        const int a = J1[G * 8 + k], b = J2[G * 8 + k];
        const int a3 = a * 3, b3 = b * 3;
        float dx = sr[b3] - sr[a3];
        float dy = sr[b3 + 1] - sr[a3 + 1];
        float dz = sr[b3 + 2] - sr[a3 + 2];
        float rl = __builtin_amdgcn_sqrtf(dx * dx + dy * dy + dz * dz);
        unsigned int v = (unsigned int)(sm[a] & sm[b]);
        float d = plen[k] - rl;
        num += v ? d * d : 0.0f;
        den += v;
    }
}

__device__ __forceinline__ void lens_sw(int wave, const float* __restrict__ sp,
                                        float* __restrict__ plen) {
    switch (wave) {
        case 0: do_lens<0>(sp, plen); break;
        case 1: do_lens<1>(sp, plen); break;
        case 2: do_lens<2>(sp, plen); break;
        default: do_lens<3>(sp, plen); break;
    }
}
__device__ __forceinline__ void acc_sw(int wave, const float* __restrict__ sr,
                                       const unsigned char* __restrict__ sm,
                                       const float* __restrict__ plen,
                                       float& num, unsigned int& den) {
    switch (wave) {
        case 0: do_acc<0>(sr, sm, plen, num, den); break;
        case 1: do_acc<1>(sr, sm, plen, num, den); break;
        case 2: do_acc<2>(sr, sm, plen, num, den); break;
        default: do_acc<3>(sr, sm, plen, num, den); break;
    }
}

__global__ __launch_bounds__(BLOCK, 2)
void bone_main(const float* __restrict__ pred, const float* __restrict__ ref,
               const void* __restrict__ mask, int B,
               unsigned int* __restrict__ ws, float* __restrict__ out) {
    __shared__ __align__(16) float4 s_pred[TF4];            // 28416 B
    __shared__ __align__(16) float4 s_ref[TF4];             // 28416 B
    __shared__ __align__(16) unsigned int s_maskw[2][TMW];  //  4736 B
    __shared__ float s_rn[WPB];
    __shared__ unsigned int s_rd[WPB];

    const int tid  = threadIdx.x;
    const int wave = tid >> 6;
    const int lane = tid & 63;          // = row within the 64-row tile

    const bool mask_bytes = (ws[2] != 0);
    const int ntiles = B / TROWS;       // 8192

    const float4* __restrict__ pred4 = (const float4*)pred;
    const float4* __restrict__ ref4  = (const float4*)ref;
    const unsigned int* __restrict__ mw = (const unsigned int*)mask;
    const int* __restrict__ mi = (const int*)mask;

    float4* s_predw = s_pred + wave * WF4;
    float4* s_refw  = s_ref  + wave * WF4;

    const float* sp_row = (const float*)s_pred + lane * ROWF;
    const float* sr_row = (const float*)s_ref  + lane * ROWF;
    const unsigned char* sm_row0 = (const unsigned char*)s_maskw[0] + lane * NKPT;
    const unsigned char* sm_row1 = (const unsigned char*)s_maskw[1] + lane * NKPT;

    float num = 0.0f;
    unsigned int den = 0u;

    if (mask_bytes) {
        // ---- pipelined path: counted vmcnt, raw barriers ----
        int t = blockIdx.x;
        int par = 0;
        if (t < ntiles) {
            // prologue: pred(t0) + mask(t0) in flight (10 loads/wave)
            stage_pose(pred4 + (size_t)t * TF4 + wave * WF4, s_predw, lane);
            stage_mask(mw + (size_t)t * TMW + wave * WMW,
                       &s_maskw[0][wave * WMW], lane);
        }
        for (; t < ntiles; t += GRID) {
            // issue ref(t): 7 loads/wave -> memory busy during the wait below
            stage_pose(ref4 + (size_t)t * TF4 + wave * WF4, s_refw, lane);
            WAITVM(7);                  // pred(t)+mask(t) landed; ref(t) in flight
            BAR();
            float plen[8];
            lens_sw(wave, sp_row, plen);
            WAITLGKM();                 // lens reads complete before overwrite
            BAR();
            const int tn = t + GRID;
            if (tn < ntiles) {
                // prefetch pred(t+G)+mask(t+G): 10 loads/wave
                stage_pose(pred4 + (size_t)tn * TF4 + wave * WF4, s_predw, lane);
                stage_mask(mw + (size_t)tn * TMW + wave * WMW,
                           &s_maskw[par ^ 1][wave * WMW], lane);
                WAITVM(10);             // ref(t) landed; prefetch in flight
            } else {
                WAITVM(0);              // last tile: nothing to keep in flight
            }
            BAR();
            acc_sw(wave, sr_row, par ? sm_row1 : sm_row0, plen, num, den);
            WAITLGKM();                 // acc reads complete before overwrite
            BAR();
            par ^= 1;
        }
    } else {
        // ---- int32-mask fallback: fully drained, correct but slow ----
        for (int t = blockIdx.x; t < ntiles; t += GRID) {
            stage_pose(pred4 + (size_t)t * TF4 + wave * WF4, s_predw, lane);
            stage_pose(ref4  + (size_t)t * TF4 + wave * WF4, s_refw,  lane);
            unsigned char* smb = (unsigned char*)s_maskw[0];
            const int* mb = mi + (size_t)t * TMB;
            for (int i = tid; i < TMB; i += BLOCK)
                smb[i] = (unsigned char)mb[i];
            __syncthreads();
            float plen[8];
            lens_sw(wave, sp_row, plen);
            acc_sw(wave, sr_row, sm_row0, plen, num, den);
            __syncthreads();
        }
    }

    // ---- reduce: wave shuffle -> block partials -> one atomic per block ----
#pragma unroll
    for (int off = 32; off > 0; off >>= 1) {
        num += __shfl_down(num, off, 64);
        den += __shfl_down(den, off, 64);
    }
    if (lane == 0) { s_rn[wave] = num; s_rd[wave] = den; }
    __syncthreads();
    if (tid == 0) {
        float n = s_rn[0] + s_rn[1] + s_rn[2] + s_rn[3];
        unsigned int d = s_rd[0] + s_rd[1] + s_rd[2] + s_rd[3];
        atomicAdd((float*)&ws[0], n);
        atomicAdd(&ws[1], d);
        __threadfence();
        unsigned int prev = atomicAdd(&ws[3], 1u);
        if (prev == (unsigned int)(gridDim.x - 1)) {
            float fn = atomicAdd((float*)&ws[0], 0.0f);
            unsigned int fd = atomicAdd(&ws[1], 0u);
            out[0] = fn / (float)fd;
        }
    }
}

extern "C" void kernel_launch(void* const* d_in, const int* in_sizes, int n_in,
                              void* d_out, int out_size, void* d_ws, size_t ws_size,
                              hipStream_t stream) {
    const float* pred = (const float*)d_in[0];
    const float* ref  = (const float*)d_in[1];
    const void*  mask = d_in[2];
    const int n_mask  = in_sizes[2];           // 524288 * 37 elements
    const int B       = n_mask / NKPT;
    unsigned int* ws  = (unsigned int*)d_ws;

    init_detect<<<1, BLOCK, 0, stream>>>((const unsigned int*)mask, ws);
    bone_main<<<GRID, BLOCK, 0, stream>>>(pred, ref, mask, B, ws, (float*)d_out);
}